// Round 6
// baseline (270.015 us; speedup 1.0000x reference)
//
#include <hip/hip_runtime.h>
#include <cstdint>

typedef __bf16 bf16x8 __attribute__((ext_vector_type(8)));
typedef unsigned short u16x8 __attribute__((ext_vector_type(8)));
typedef unsigned short u16x4 __attribute__((ext_vector_type(4)));
typedef float f32x4 __attribute__((ext_vector_type(4)));

// B=16, S=1024, D=512, T=3, BT=48
// Xb [bt][s][d] bf16 ; Xt [bt][d][s] bf16 ; Gb [bt][s][d'] bf16 (= X * (SC*Wq^T*Wk))
// Sb: [bt_local][q][k] fp16 scores -> bf16 P=w_t*exp/l in place
// Z  [b][s][d] bf16 (= sum_t P_t X_t), overlays Gb after qk ; out = Z*Wv^T + bv

__device__ __forceinline__ unsigned short f2bf(float x){
  unsigned u = __float_as_uint(x);
  u += 0x7fffu + ((u >> 16) & 1u);
  return (unsigned short)(u >> 16);
}

__device__ __forceinline__ void gload16(const void* src, void* dst){
  auto g = reinterpret_cast<const uint32_t __attribute__((address_space(1)))*>(
             reinterpret_cast<uintptr_t>(src));
  auto l = reinterpret_cast<uint32_t __attribute__((address_space(3)))*>(
             reinterpret_cast<uintptr_t>(dst));
  __builtin_amdgcn_global_load_lds(g, l, 16, 0, 0);
}

// stage one 128x64 bf16 tile: linear LDS chunks, inverse-swizzled global source.
__device__ __forceinline__ void stage_tile(const unsigned short* __restrict__ g, size_t ld,
                                           unsigned short* l, int tid){
  #pragma unroll
  for (int i = 0; i < 4; ++i){
    int j = i * 256 + tid;
    int r = j >> 3, cc = j & 7;
    int c = cc ^ (r & 7);
    gload16(g + (size_t)r * ld + c * 8, l + (size_t)(i * 256 + (tid & 192)) * 8);
  }
}

__device__ __forceinline__ bf16x8 frag_at(const unsigned short* l, int row, int kch){
  int ch = kch ^ (row & 7);
  return *(const bf16x8*)(l + (row << 6) + (ch << 3));
}

// ---------- merged prologue: conv_wt (blocks 0-127), conv_wv (128-255), w1 (256-263) ----------
__global__ void k_prep(const float* __restrict__ Wq, const float* __restrict__ Wk,
                       const float* __restrict__ Wv, const float* __restrict__ bq,
                       unsigned short* __restrict__ WqT, unsigned short* __restrict__ WkT,
                       unsigned short* __restrict__ Wv16, float* __restrict__ w1){
  __shared__ float sh[64 * 65];
  const int bi = blockIdx.x;
  const int tid = threadIdx.x;
  if (bi < 128){
    const float* src = (bi & 64) ? Wk : Wq;
    unsigned short* dst = (bi & 64) ? WkT : WqT;
    int te = (bi >> 3) & 7, td = bi & 7;
    #pragma unroll
    for (int i = 0; i < 4; ++i){
      int q = i * 256 + tid;
      int r = q >> 4, c4 = q & 15;
      f32x4 v = *(const f32x4*)(src + (size_t)(te * 64 + r) * 512 + td * 64 + c4 * 4);
      sh[r * 65 + c4 * 4 + 0] = v[0]; sh[r * 65 + c4 * 4 + 1] = v[1];
      sh[r * 65 + c4 * 4 + 2] = v[2]; sh[r * 65 + c4 * 4 + 3] = v[3];
    }
    __syncthreads();
    #pragma unroll
    for (int i = 0; i < 2; ++i){
      int q = i * 256 + tid;
      int r = q >> 3, c8 = q & 7;
      u16x8 o;
      #pragma unroll
      for (int j = 0; j < 8; ++j) o[j] = f2bf(sh[(c8 * 8 + j) * 65 + r]);
      *(u16x8*)(dst + (size_t)(td * 64 + r) * 512 + te * 64 + c8 * 8) = o;
    }
  } else if (bi < 256){
    size_t e = ((size_t)(bi - 128) * 256 + tid) * 8;
    f32x4 v0 = *(const f32x4*)(Wv + e), v1 = *(const f32x4*)(Wv + e + 4);
    u16x8 o;
    o[0] = f2bf(v0[0]); o[1] = f2bf(v0[1]); o[2] = f2bf(v0[2]); o[3] = f2bf(v0[3]);
    o[4] = f2bf(v1[0]); o[5] = f2bf(v1[1]); o[6] = f2bf(v1[2]); o[7] = f2bf(v1[3]);
    *(u16x8*)(Wv16 + e) = o;
  } else {
    int d = (bi - 256) * 64 + (tid & 63);
    int eq = tid >> 6;
    float s = 0.f;
    #pragma unroll 8
    for (int e = eq * 128; e < eq * 128 + 128; ++e) s += Wk[(size_t)e * 512 + d] * bq[e];
    sh[eq * 64 + (tid & 63)] = s;
    __syncthreads();
    if (eq == 0)
      w1[d] = (sh[tid] + sh[64 + tid] + sh[128 + tid] + sh[192 + tid]) * 0.04419417382415922f;
  }
}

// ---------- features fp32 -> bf16 Xb (row-major) + Xt (transposed) + vcol = X*w1 ----------
// grid 6144 = 48 bt x 16 s-tiles x 8 d-tiles of 64x64; vcol must be pre-zeroed.
__global__ void k_conv(const float* __restrict__ f0, const float* __restrict__ f1,
                       const float* __restrict__ f2, const float* __restrict__ w1,
                       unsigned short* __restrict__ Xb, unsigned short* __restrict__ Xt,
                       float* __restrict__ vcol){
  __shared__ float tl[64 * 65];
  const int bi = blockIdx.x;
  const int tid = threadIdx.x;
  const int bt = bi >> 7;
  const int st = (bi >> 3) & 15, dt = bi & 7;
  const int b = bt / 3, t = bt % 3;
  const int s0 = st * 64, d0 = dt * 64;
  const float* src = (t == 0 ? f0 : (t == 1 ? f1 : f2)) + ((size_t)b << 19)
                   + (size_t)s0 * 512 + d0;
  #pragma unroll
  for (int q = 0; q < 4; ++q){
    int j = q * 256 + tid;
    int r = j >> 4, c4 = (j & 15) * 4;
    f32x4 v = *(const f32x4*)(src + (size_t)r * 512 + c4);
    // Xb (row-major bf16)
    u16x4 o;
    o[0] = f2bf(v[0]); o[1] = f2bf(v[1]); o[2] = f2bf(v[2]); o[3] = f2bf(v[3]);
    *(u16x4*)(Xb + ((size_t)bt << 19) + (size_t)(s0 + r) * 512 + d0 + c4) = o;
    // LDS f32 tile (padded 65)
    tl[r * 65 + c4 + 0] = v[0]; tl[r * 65 + c4 + 1] = v[1];
    tl[r * 65 + c4 + 2] = v[2]; tl[r * 65 + c4 + 3] = v[3];
    // vcol partial: dot with w1 segment, reduce over the 16 lanes sharing row r
    f32x4 wv = *(const f32x4*)(w1 + d0 + c4);
    float p = v[0]*wv[0] + v[1]*wv[1] + v[2]*wv[2] + v[3]*wv[3];
    p += __shfl_xor(p, 1); p += __shfl_xor(p, 2);
    p += __shfl_xor(p, 4); p += __shfl_xor(p, 8);
    if ((tid & 15) == 0) atomicAdd(vcol + ((size_t)bt << 10) + s0 + r, p);
  }
  __syncthreads();
  // transposed write: Xt[d][s]
  #pragma unroll
  for (int q = 0; q < 2; ++q){
    int j = q * 256 + tid;
    int d = j >> 3, sc = (j & 7) * 8;
    u16x8 o;
    #pragma unroll
    for (int k = 0; k < 8; ++k) o[k] = f2bf(tl[(sc + k) * 65 + d]);
    *(u16x8*)(Xt + ((size_t)bt << 19) + (size_t)(d0 + d) * 1024 + s0 + sc) = o;
  }
}

// ---------- C(bf16) = A * B^T * scale. K=512. grid = (M/128)*(N/128), XCD-chunked ----------
__global__ __launch_bounds__(256, 2)
void k_gemm_nt(const unsigned short* __restrict__ A, const unsigned short* __restrict__ Bm,
               unsigned short* __restrict__ C, int N, float scale){
  __shared__ __align__(16) unsigned short Al[2][8192];
  __shared__ __align__(16) unsigned short Bl[2][8192];
  const int tid = threadIdx.x;
  const int l  = tid & 63;
  const int wid = tid >> 6;
  const int lr = l & 15;
  const int lg = l >> 4;
  const int cpx = gridDim.x >> 3;
  const int wg = (blockIdx.x & 7) * cpx + (blockIdx.x >> 3);
  const int nbc = N >> 7;
  const int rb = wg / nbc, cb = wg % nbc;
  const unsigned short* Ab = A + (size_t)rb * 128 * 512;
  const unsigned short* Bb = Bm + (size_t)cb * 128 * 512;

  const f32x4 zero4 = {0.f, 0.f, 0.f, 0.f};
  f32x4 acc[4][4];
  #pragma unroll
  for (int i = 0; i < 4; ++i)
    #pragma unroll
    for (int j = 0; j < 4; ++j) acc[i][j] = zero4;

  stage_tile(Ab, 512, &Al[0][0], tid);
  stage_tile(Bb, 512, &Bl[0][0], tid);
  __syncthreads();

  const int wr = wid >> 1, wc = wid & 1;

  for (int kb = 0; kb < 8; ++kb){
    const int cur = kb & 1;
    if (kb < 7){
      stage_tile(Ab + (kb + 1) * 64, 512, &Al[cur ^ 1][0], tid);
      stage_tile(Bb + (kb + 1) * 64, 512, &Bl[cur ^ 1][0], tid);
    }
    #pragma unroll
    for (int ks = 0; ks < 2; ++ks){
      bf16x8 af[4], bf[4];
      #pragma unroll
      for (int i = 0; i < 4; ++i) af[i] = frag_at(&Al[cur][0], wr * 64 + i * 16 + lr, ks * 4 + lg);
      #pragma unroll
      for (int j = 0; j < 4; ++j) bf[j] = frag_at(&Bl[cur][0], wc * 64 + j * 16 + lr, ks * 4 + lg);
      #pragma unroll
      for (int i = 0; i < 4; ++i)
        #pragma unroll
        for (int j = 0; j < 4; ++j)
          acc[i][j] = __builtin_amdgcn_mfma_f32_16x16x32_bf16(af[i], bf[j], acc[i][j], 0, 0, 0);
    }
    __syncthreads();
  }

  unsigned short* eL = &Al[0][0];
  #pragma unroll
  for (int j = 0; j < 4; ++j){
    int lcol = wc * 64 + j * 16 + lr;
    #pragma unroll
    for (int i = 0; i < 4; ++i){
      int lrow0 = wr * 64 + i * 16 + lg * 4;
      #pragma unroll
      for (int r = 0; r < 4; ++r)
        eL[(lrow0 + r) * 128 + lcol] = f2bf(acc[i][j][r] * scale);
    }
  }
  __syncthreads();
  #pragma unroll
  for (int q = 0; q < 8; ++q){
    int idx = q * 256 + tid;
    int row = idx >> 4, col = (idx & 15) * 8;
    *(u16x8*)(&C[(size_t)(rb * 128 + row) * N + cb * 128 + col]) =
        *(const u16x8*)(&eL[row * 128 + col]);
  }
}

// ---------- S = G * X^T, fp16 out. grid = nbt*64, XCD-chunked. ----------
__global__ __launch_bounds__(256, 2)
void k_gemm_qk(const unsigned short* __restrict__ Gb, const unsigned short* __restrict__ Xb,
               unsigned short* __restrict__ S, int bt0){
  __shared__ __align__(16) unsigned short Al[2][8192];
  __shared__ __align__(16) unsigned short Bl[2][8192];
  const int tid = threadIdx.x;
  const int l  = tid & 63;
  const int wid = tid >> 6;
  const int lr = l & 15;
  const int lg = l >> 4;
  const int cpx = gridDim.x >> 3;
  const int wg = (blockIdx.x & 7) * cpx + (blockIdx.x >> 3);
  const int btl = wg >> 6;
  const int bt = bt0 + btl;
  const int tile = wg & 63;
  const int rb = tile >> 3, cb = tile & 7;
  const unsigned short* Ab = Gb + ((size_t)bt << 19) + (size_t)rb * 128 * 512;
  const unsigned short* Bb = Xb + ((size_t)bt << 19) + (size_t)cb * 128 * 512;
  unsigned short* Cb = S + ((size_t)btl << 20);

  const f32x4 zero4 = {0.f, 0.f, 0.f, 0.f};
  f32x4 acc[4][4];
  #pragma unroll
  for (int i = 0; i < 4; ++i)
    #pragma unroll
    for (int j = 0; j < 4; ++j) acc[i][j] = zero4;

  stage_tile(Ab, 512, &Al[0][0], tid);
  stage_tile(Bb, 512, &Bl[0][0], tid);
  __syncthreads();

  const int wr = wid >> 1, wc = wid & 1;

  for (int kb = 0; kb < 8; ++kb){
    const int cur = kb & 1;
    if (kb < 7){
      stage_tile(Ab + (kb + 1) * 64, 512, &Al[cur ^ 1][0], tid);
      stage_tile(Bb + (kb + 1) * 64, 512, &Bl[cur ^ 1][0], tid);
    }
    #pragma unroll
    for (int ks = 0; ks < 2; ++ks){
      bf16x8 af[4], bf[4];
      #pragma unroll
      for (int i = 0; i < 4; ++i) af[i] = frag_at(&Al[cur][0], wr * 64 + i * 16 + lr, ks * 4 + lg);
      #pragma unroll
      for (int j = 0; j < 4; ++j) bf[j] = frag_at(&Bl[cur][0], wc * 64 + j * 16 + lr, ks * 4 + lg);
      #pragma unroll
      for (int i = 0; i < 4; ++i)
        #pragma unroll
        for (int j = 0; j < 4; ++j)
          acc[i][j] = __builtin_amdgcn_mfma_f32_16x16x32_bf16(af[i], bf[j], acc[i][j], 0, 0, 0);
    }
    __syncthreads();
  }

  unsigned short* eL = &Al[0][0];
  #pragma unroll
  for (int j = 0; j < 4; ++j){
    int lcol = wc * 64 + j * 16 + lr;
    #pragma unroll
    for (int i = 0; i < 4; ++i){
      int lrow0 = wr * 64 + i * 16 + lg * 4;
      #pragma unroll
      for (int r = 0; r < 4; ++r){
        _Float16 h = (_Float16)acc[i][j][r];
        eL[(lrow0 + r) * 128 + lcol] = __builtin_bit_cast(unsigned short, h);
      }
    }
  }
  __syncthreads();
  #pragma unroll
  for (int q = 0; q < 8; ++q){
    int idx = q * 256 + tid;
    int row = idx >> 4, col = (idx & 15) * 8;
    *(u16x8*)(&Cb[((size_t)(rb * 128 + row) << 10) + cb * 128 + col]) =
        *(const u16x8*)(&eL[row * 128 + col]);
  }
}

// ---------- softmax rows in place: fp16 S (+vcol bias) -> bf16 P = w[t]*exp/l ----------
__global__ __launch_bounds__(256)
void k_softmax(unsigned short* __restrict__ S, const float* __restrict__ vcol,
               const float* __restrict__ tfw, int bt0){
  const int wid = threadIdx.x >> 6, l = threadIdx.x & 63;
  const size_t row = (size_t)blockIdx.x * 4 + wid;
  const int bt = bt0 + (int)(row >> 10);
  const int t = bt % 3;
  float t0 = tfw[0], t1 = tfw[1], t2 = tfw[2];
  float tm = fmaxf(t0, fmaxf(t1, t2));
  float e0 = __expf(t0 - tm), e1 = __expf(t1 - tm), e2 = __expf(t2 - tm);
  float w = (t == 0 ? e0 : (t == 1 ? e1 : e2)) / (e0 + e1 + e2);

  const float* vr = vcol + ((size_t)bt << 10) + l * 16;
  unsigned short* rp = S + (row << 10) + l * 16;
  u16x8 a = *(const u16x8*)rp;
  u16x8 b = *(const u16x8*)(rp + 8);
  f32x4 va0 = *(const f32x4*)(vr), va1 = *(const f32x4*)(vr + 4);
  f32x4 va2 = *(const f32x4*)(vr + 8), va3 = *(const f32x4*)(vr + 12);
  float x[16];
  #pragma unroll
  for (int j = 0; j < 8; ++j){
    x[j]     = (float)__builtin_bit_cast(_Float16, (unsigned short)a[j]);
    x[8 + j] = (float)__builtin_bit_cast(_Float16, (unsigned short)b[j]);
  }
  x[0] += va0[0]; x[1] += va0[1]; x[2]  += va0[2]; x[3]  += va0[3];
  x[4] += va1[0]; x[5] += va1[1]; x[6]  += va1[2]; x[7]  += va1[3];
  x[8] += va2[0]; x[9] += va2[1]; x[10] += va2[2]; x[11] += va2[3];
  x[12]+= va3[0]; x[13]+= va3[1]; x[14] += va3[2]; x[15] += va3[3];
  float m = x[0];
  #pragma unroll
  for (int j = 1; j < 16; ++j) m = fmaxf(m, x[j]);
  m = fmaxf(m, __shfl_xor(m, 1));
  m = fmaxf(m, __shfl_xor(m, 2));
  m = fmaxf(m, __shfl_xor(m, 4));
  m = fmaxf(m, __shfl_xor(m, 8));
  m = fmaxf(m, __shfl_xor(m, 16));
  m = fmaxf(m, __shfl_xor(m, 32));
  float s = 0.f;
  #pragma unroll
  for (int j = 0; j < 16; ++j){ x[j] = __expf(x[j] - m); s += x[j]; }
  s += __shfl_xor(s, 1);
  s += __shfl_xor(s, 2);
  s += __shfl_xor(s, 4);
  s += __shfl_xor(s, 8);
  s += __shfl_xor(s, 16);
  s += __shfl_xor(s, 32);
  float sc = w / s;
  u16x8 oa, ob;
  #pragma unroll
  for (int j = 0; j < 8; ++j){
    oa[j] = f2bf(x[j] * sc);
    ob[j] = f2bf(x[8 + j] * sc);
  }
  *(u16x8*)rp = oa;
  *(u16x8*)(rp + 8) = ob;
}

// ---------- Z[b] = sum_t P[b,t] * X[b,t]  (bf16 out, K=3072). grid = nb*32 ----------
__global__ __launch_bounds__(256, 2)
void k_gemm_px(const unsigned short* __restrict__ P, const unsigned short* __restrict__ Xt,
               unsigned short* __restrict__ Z, int b0){
  __shared__ __align__(16) unsigned short Al[2][8192];
  __shared__ __align__(16) unsigned short Bl[2][8192];
  const int tid = threadIdx.x;
  const int l  = tid & 63;
  const int wid = tid >> 6;
  const int lr = l & 15;
  const int lg = l >> 4;
  const int cpx = gridDim.x >> 3;
  const int wg = (blockIdx.x & 7) * cpx + (blockIdx.x >> 3);
  const int bl = wg >> 5;
  const int b = b0 + bl;
  const int tile = wg & 31;
  const int rb = tile >> 2, cb = tile & 3;

  const f32x4 zero4 = {0.f, 0.f, 0.f, 0.f};
  f32x4 acc[4][4];
  #pragma unroll
  for (int i = 0; i < 4; ++i)
    #pragma unroll
    for (int j = 0; j < 4; ++j) acc[i][j] = zero4;

  {
    const unsigned short* Ab = P  + ((size_t)(bl * 3) << 20) + (size_t)rb * 128 * 1024;
    const unsigned short* Bb = Xt + ((size_t)(b * 3) << 19) + (size_t)cb * 128 * 1024;
    stage_tile(Ab, 1024, &Al[0][0], tid);
    stage_tile(Bb, 1024, &Bl[0][0], tid);
  }
  __syncthreads();

  const int wr = wid >> 1, wc = wid & 1;

  #pragma unroll 2
  for (int kb = 0; kb < 48; ++kb){
    const int cur = kb & 1;
    if (kb < 47){
      int kn = kb + 1;
      int t = kn >> 4, kk = kn & 15;
      const unsigned short* Ab = P  + ((size_t)(bl * 3 + t) << 20) + (size_t)rb * 128 * 1024 + kk * 64;
      const unsigned short* Bb = Xt + ((size_t)(b * 3 + t) << 19) + (size_t)cb * 128 * 1024 + kk * 64;
      stage_tile(Ab, 1024, &Al[cur ^ 1][0], tid);
      stage_tile(Bb, 1024, &Bl[cur ^ 1][0], tid);
    }
    #pragma unroll
    for (int ks = 0; ks < 2; ++ks){
      bf16x8 af[4], bf[4];
      #pragma unroll
      for (int i = 0; i < 4; ++i) af[i] = frag_at(&Al[cur][0], wr * 64 + i * 16 + lr, ks * 4 + lg);
      #pragma unroll
      for (int j = 0; j < 4; ++j) bf[j] = frag_at(&Bl[cur][0], wc * 64 + j * 16 + lr, ks * 4 + lg);
      #pragma unroll
      for (int i = 0; i < 4; ++i)
        #pragma unroll
        for (int j = 0; j < 4; ++j)
          acc[i][j] = __builtin_amdgcn_mfma_f32_16x16x32_bf16(af[i], bf[j], acc[i][j], 0, 0, 0);
    }
    __syncthreads();
  }

  // epilogue: bf16 Z[b][q][d] via LDS, coalesced
  unsigned short* eL = &Al[0][0];
  #pragma unroll
  for (int j = 0; j < 4; ++j){
    int lcol = wc * 64 + j * 16 + lr;
    #pragma unroll
    for (int i = 0; i < 4; ++i){
      int lrow0 = wr * 64 + i * 16 + lg * 4;
      #pragma unroll
      for (int r = 0; r < 4; ++r)
        eL[(lrow0 + r) * 128 + lcol] = f2bf(acc[i][j][r]);
    }
  }
  __syncthreads();
  unsigned short* Cb = Z + ((size_t)b << 19);
  #pragma unroll
  for (int q = 0; q < 8; ++q){
    int idx = q * 256 + tid;
    int row = idx >> 4, col = (idx & 15) * 8;
    *(u16x8*)(&Cb[(size_t)(rb * 128 + row) * 512 + cb * 128 + col]) =
        *(const u16x8*)(&eL[row * 128 + col]);
  }
}

// ---------- out(f32) = Z * Wv^T + bv. M=16384, N=512, K=512. grid 512 ----------
__global__ __launch_bounds__(256, 2)
void k_gemm_zo(const unsigned short* __restrict__ Z, const unsigned short* __restrict__ Wv16,
               const float* __restrict__ bv, float* __restrict__ out){
  __shared__ __align__(16) unsigned short SH[32768];   // 64 KB
  unsigned short* Al0 = SH;
  unsigned short* Al1 = SH + 8192;
  unsigned short* Bl0 = SH + 16384;
  unsigned short* Bl1 = SH + 24576;
  const int tid = threadIdx.x;
  const int l  = tid & 63;
  const int wid = tid >> 6;
  const int lr = l & 15;
  const int lg = l >> 4;
  const int cpx = gridDim.x >> 3;
  const int wg = (blockIdx.x & 7) * cpx + (blockIdx.x >> 3);
  const int rb = wg >> 2, cb = wg & 3;
  const unsigned short* Ab = Z + (size_t)rb * 128 * 512;
  const unsigned short* Bb = Wv16 + (size_t)cb * 128 * 512;

  const f32x4 zero4 = {0.f, 0.f, 0.f, 0.f};
  f32x4 acc[4][4];
  #pragma unroll
  for (int i = 0; i < 4; ++i)
    #pragma unroll
    for (int j = 0; j < 4; ++j) acc[i][j] = zero4;

  stage_tile(Ab, 512, Al0, tid);
  stage_tile(Bb, 512, Bl0, tid);
  __syncthreads();

  const int wr = wid >> 1, wc = wid & 1;

  for (int kb = 0; kb < 8; ++kb){
    unsigned short* Acur = (kb & 1) ? Al1 : Al0;
    unsigned short* Bcur = (kb & 1) ? Bl1 : Bl0;
    if (kb < 7){
      stage_tile(Ab + (kb + 1) * 64, 512, (kb & 1) ? Al0 : Al1, tid);
      stage_tile(Bb + (kb + 1) * 64, 512, (kb & 1) ? Bl0 : Bl1, tid);
    }
    #pragma unroll
    for (int ks = 0; ks < 2; ++ks){
      bf16x8 af[4], bf[4];
      #pragma unroll
      for (int i = 0; i < 4; ++i) af[i] = frag_at(Acur, wr * 64 + i * 16 + lr, ks * 4 + lg);
      #pragma unroll
      for (int j = 0; j < 4; ++j) bf[j] = frag_at(Bcur, wc * 64 + j * 16 + lr, ks * 4 + lg);
      #pragma unroll
      for (int i = 0; i < 4; ++i)
        #pragma unroll
        for (int j = 0; j < 4; ++j)
          acc[i][j] = __builtin_amdgcn_mfma_f32_16x16x32_bf16(af[i], bf[j], acc[i][j], 0, 0, 0);
    }
    __syncthreads();
  }

  // f32 epilogue via full 64KB LDS
  float* eF = (float*)SH;
  #pragma unroll
  for (int j = 0; j < 4; ++j){
    int lcol = wc * 64 + j * 16 + lr;
    float bc = bv[cb * 128 + lcol];
    #pragma unroll
    for (int i = 0; i < 4; ++i){
      int lrow0 = wr * 64 + i * 16 + lg * 4;
      #pragma unroll
      for (int r = 0; r < 4; ++r)
        eF[(lrow0 + r) * 128 + lcol] = acc[i][j][r] + bc;
    }
  }
  __syncthreads();
  #pragma unroll
  for (int q = 0; q < 16; ++q){
    int idx = q * 256 + tid;
    int row = idx >> 5, c4 = (idx & 31) * 4;
    *(f32x4*)(&out[(size_t)(rb * 128 + row) * 512 + cb * 128 + c4]) =
        *(const f32x4*)(&eF[row * 128 + c4]);
  }
}

extern "C" void kernel_launch(void* const* d_in, const int* in_sizes, int n_in,
                              void* d_out, int out_size, void* d_ws, size_t ws_size,
                              hipStream_t stream){
  (void)in_sizes; (void)n_in; (void)out_size;
  const float* f4h = (const float*)d_in[0];
  const float* f1d = (const float*)d_in[1];
  const float* f1w = (const float*)d_in[2];
  const float* Wq  = (const float*)d_in[3];
  const float* bq  = (const float*)d_in[4];
  const float* Wk  = (const float*)d_in[5];
  const float* bk  = (const float*)d_in[6];
  const float* Wv  = (const float*)d_in[7];
  const float* bv  = (const float*)d_in[8];
  const float* tfw = (const float*)d_in[9];
  (void)bk;  // row-constant in scores: cancels in softmax
  float* out = (float*)d_out;

  const size_t N48 = (size_t)48 * 1024 * 512;
  unsigned short* Gb   = (unsigned short*)d_ws;    // also Z region after qk consumes Gb
  unsigned short* Xb   = Gb + N48;
  unsigned short* Xt   = Xb + N48;
  float*          vcol = (float*)(Xt + N48);       // 49152 f32
  unsigned short* Wv16 = (unsigned short*)(vcol + 49152);
  unsigned short* WqT  = Wv16 + 262144;            // Sb overlay starts here
  unsigned short* WkT  = WqT + 262144;
  unsigned short* Mt   = WkT + 262144;
  float*          w1   = (float*)(Mt + 262144);    // dead before Sb is written
  unsigned short* Sb   = WqT;
  unsigned short* Zb   = Gb;

  const float SC = 0.04419417382415922f;           // 1/sqrt(512)
  const size_t base = 3 * N48 * 2 + 49152 * 4 + 262144 * 2;   // bytes before Sb
  const size_t s_full = (size_t)48 * 1024 * 1024 * 2;

  hipMemsetAsync(vcol, 0, 49152 * 4, stream);
  k_prep<<<264, 256, 0, stream>>>(Wq, Wk, Wv, bq, WqT, WkT, Wv16, w1);
  k_conv<<<6144, 256, 0, stream>>>(f4h, f1d, f1w, w1, Xb, Xt, vcol);
  k_gemm_nt<<<16, 256, 0, stream>>>(WkT, WqT, Mt, 512, SC);     // Mt = SC*WkT*WqT^T
  k_gemm_nt<<<1536, 256, 0, stream>>>(Xb, Mt, Gb, 512, 1.0f);   // Gb = Xb * Mt^T

  if (ws_size >= base + s_full){
    k_gemm_qk<<<3072, 256, 0, stream>>>(Gb, Xb, Sb, 0);
    k_softmax<<<12288, 256, 0, stream>>>(Sb, vcol, tfw, 0);
    k_gemm_px<<<512, 256, 0, stream>>>(Sb, Xt, Zb, 0);
  } else {
    for (int h = 0; h < 2; ++h){
      int bt0 = h * 24;
      k_gemm_qk<<<1536, 256, 0, stream>>>(Gb, Xb, Sb, bt0);
      k_softmax<<<6144, 256, 0, stream>>>(Sb, vcol, tfw, bt0);
      k_gemm_px<<<256, 256, 0, stream>>>(Sb, Xt, Zb, h * 8);
    }
  }
  k_gemm_zo<<<512, 256, 0, stream>>>(Zb, Wv16, bv, out);
}

// Round 7
// 267.846 us; speedup vs baseline: 1.0081x; 1.0081x over previous
//
#include <hip/hip_runtime.h>
#include <cstdint>

typedef __bf16 bf16x8 __attribute__((ext_vector_type(8)));
typedef unsigned short u16x8 __attribute__((ext_vector_type(8)));
typedef unsigned short u16x4 __attribute__((ext_vector_type(4)));
typedef float f32x4 __attribute__((ext_vector_type(4)));

// B=16, S=1024, D=512, T=3, BT=48
// Xb [bt][s][d] bf16 ; Xt [bt][d][s] bf16 ; Gb [bt][s][d'] bf16 (= X * (SC*Wq^T*Wk))
// Sb: [bt][q][k] fp16 scores -> bf16 P=w_t*exp/l in place
// Z  [b][s][d] bf16 (= sum_t P_t X_t), overlays Gb ; out = Z*Wv^T + bv

__device__ __forceinline__ unsigned short f2bf(float x){
  unsigned u = __float_as_uint(x);
  u += 0x7fffu + ((u >> 16) & 1u);
  return (unsigned short)(u >> 16);
}

__device__ __forceinline__ void gload16(const void* src, void* dst){
  auto g = reinterpret_cast<const uint32_t __attribute__((address_space(1)))*>(
             reinterpret_cast<uintptr_t>(src));
  auto l = reinterpret_cast<uint32_t __attribute__((address_space(3)))*>(
             reinterpret_cast<uintptr_t>(dst));
  __builtin_amdgcn_global_load_lds(g, l, 16, 0, 0);
}

// stage one 128x64 bf16 tile: linear LDS chunks, inverse-swizzled global source.
__device__ __forceinline__ void stage_tile(const unsigned short* __restrict__ g, size_t ld,
                                           unsigned short* l, int tid){
  #pragma unroll
  for (int i = 0; i < 4; ++i){
    int j = i * 256 + tid;
    int r = j >> 3, cc = j & 7;
    int c = cc ^ (r & 7);
    gload16(g + (size_t)r * ld + c * 8, l + (size_t)(i * 256 + (tid & 192)) * 8);
  }
}

__device__ __forceinline__ bf16x8 frag_at(const unsigned short* l, int row, int kch){
  int ch = kch ^ (row & 7);
  return *(const bf16x8*)(l + (row << 6) + (ch << 3));
}

// ---------- merged prologue: conv_wt (0-127), conv_wv (128-255), w1 (256-263), vcol zero (264-311) ----------
__global__ void k_prep(const float* __restrict__ Wq, const float* __restrict__ Wk,
                       const float* __restrict__ Wv, const float* __restrict__ bq,
                       unsigned short* __restrict__ WqT, unsigned short* __restrict__ WkT,
                       unsigned short* __restrict__ Wv16, float* __restrict__ w1,
                       float* __restrict__ vcol){
  __shared__ float sh[64 * 65];
  const int bi = blockIdx.x;
  const int tid = threadIdx.x;
  if (bi < 128){
    const float* src = (bi & 64) ? Wk : Wq;
    unsigned short* dst = (bi & 64) ? WkT : WqT;
    int te = (bi >> 3) & 7, td = bi & 7;
    #pragma unroll
    for (int i = 0; i < 4; ++i){
      int q = i * 256 + tid;
      int r = q >> 4, c4 = q & 15;
      f32x4 v = *(const f32x4*)(src + (size_t)(te * 64 + r) * 512 + td * 64 + c4 * 4);
      sh[r * 65 + c4 * 4 + 0] = v[0]; sh[r * 65 + c4 * 4 + 1] = v[1];
      sh[r * 65 + c4 * 4 + 2] = v[2]; sh[r * 65 + c4 * 4 + 3] = v[3];
    }
    __syncthreads();
    #pragma unroll
    for (int i = 0; i < 2; ++i){
      int q = i * 256 + tid;
      int r = q >> 3, c8 = q & 7;
      u16x8 o;
      #pragma unroll
      for (int j = 0; j < 8; ++j) o[j] = f2bf(sh[(c8 * 8 + j) * 65 + r]);
      *(u16x8*)(dst + (size_t)(td * 64 + r) * 512 + te * 64 + c8 * 8) = o;
    }
  } else if (bi < 256){
    size_t e = ((size_t)(bi - 128) * 256 + tid) * 8;
    f32x4 v0 = *(const f32x4*)(Wv + e), v1 = *(const f32x4*)(Wv + e + 4);
    u16x8 o;
    o[0] = f2bf(v0[0]); o[1] = f2bf(v0[1]); o[2] = f2bf(v0[2]); o[3] = f2bf(v0[3]);
    o[4] = f2bf(v1[0]); o[5] = f2bf(v1[1]); o[6] = f2bf(v1[2]); o[7] = f2bf(v1[3]);
    *(u16x8*)(Wv16 + e) = o;
  } else if (bi < 264){
    int d = (bi - 256) * 64 + (tid & 63);
    int eq = tid >> 6;
    float s = 0.f;
    #pragma unroll 8
    for (int e = eq * 128; e < eq * 128 + 128; ++e) s += Wk[(size_t)e * 512 + d] * bq[e];
    sh[eq * 64 + (tid & 63)] = s;
    __syncthreads();
    if (eq == 0)
      w1[d] = (sh[tid] + sh[64 + tid] + sh[128 + tid] + sh[192 + tid]) * 0.04419417382415922f;
  } else {
    // zero vcol (48 blocks x 1024 f32)
    f32x4 z = {0.f, 0.f, 0.f, 0.f};
    *(f32x4*)(vcol + ((size_t)(bi - 264) * 256 + tid) * 4) = z;
  }
}

// ---------- features fp32 -> bf16 Xb (row-major) + Xt (transposed) + vcol = X*w1 ----------
// grid 6144 = 48 bt x 16 s-tiles x 8 d-tiles of 64x64; vcol pre-zeroed by k_prep.
__global__ void k_conv(const float* __restrict__ f0, const float* __restrict__ f1,
                       const float* __restrict__ f2, const float* __restrict__ w1,
                       unsigned short* __restrict__ Xb, unsigned short* __restrict__ Xt,
                       float* __restrict__ vcol){
  __shared__ float tl[64 * 65];
  const int bi = blockIdx.x;
  const int tid = threadIdx.x;
  const int bt = bi >> 7;
  const int st = (bi >> 3) & 15, dt = bi & 7;
  const int b = bt / 3, t = bt % 3;
  const int s0 = st * 64, d0 = dt * 64;
  const float* src = (t == 0 ? f0 : (t == 1 ? f1 : f2)) + ((size_t)b << 19)
                   + (size_t)s0 * 512 + d0;
  #pragma unroll
  for (int q = 0; q < 4; ++q){
    int j = q * 256 + tid;
    int r = j >> 4, c4 = (j & 15) * 4;
    f32x4 v = *(const f32x4*)(src + (size_t)r * 512 + c4);
    u16x4 o;
    o[0] = f2bf(v[0]); o[1] = f2bf(v[1]); o[2] = f2bf(v[2]); o[3] = f2bf(v[3]);
    *(u16x4*)(Xb + ((size_t)bt << 19) + (size_t)(s0 + r) * 512 + d0 + c4) = o;
    tl[r * 65 + c4 + 0] = v[0]; tl[r * 65 + c4 + 1] = v[1];
    tl[r * 65 + c4 + 2] = v[2]; tl[r * 65 + c4 + 3] = v[3];
    f32x4 wv = *(const f32x4*)(w1 + d0 + c4);
    float p = v[0]*wv[0] + v[1]*wv[1] + v[2]*wv[2] + v[3]*wv[3];
    p += __shfl_xor(p, 1); p += __shfl_xor(p, 2);
    p += __shfl_xor(p, 4); p += __shfl_xor(p, 8);
    if ((tid & 15) == 0) atomicAdd(vcol + ((size_t)bt << 10) + s0 + r, p);
  }
  __syncthreads();
  #pragma unroll
  for (int q = 0; q < 2; ++q){
    int j = q * 256 + tid;
    int d = j >> 3, sc = (j & 7) * 8;
    u16x8 o;
    #pragma unroll
    for (int k = 0; k < 8; ++k) o[k] = f2bf(tl[(sc + k) * 65 + d]);
    *(u16x8*)(Xt + ((size_t)bt << 19) + (size_t)(d0 + d) * 1024 + s0 + sc) = o;
  }
}

// ---------- C(bf16) = A * B^T * scale. K=512. grid = (M/128)*(N/128), XCD-chunked ----------
__global__ __launch_bounds__(256, 2)
void k_gemm_nt(const unsigned short* __restrict__ A, const unsigned short* __restrict__ Bm,
               unsigned short* __restrict__ C, int N, float scale){
  __shared__ __align__(16) unsigned short SH[32768];   // 64 KB unified
  unsigned short* A0 = SH;
  unsigned short* A1 = SH + 8192;
  unsigned short* B0 = SH + 16384;
  unsigned short* B1 = SH + 24576;
  const int tid = threadIdx.x;
  const int l  = tid & 63;
  const int wid = tid >> 6;
  const int lr = l & 15;
  const int lg = l >> 4;
  const int cpx = gridDim.x >> 3;
  const int wg = (blockIdx.x & 7) * cpx + (blockIdx.x >> 3);
  const int nbc = N >> 7;
  const int rb = wg / nbc, cb = wg % nbc;
  const unsigned short* Ab = A + (size_t)rb * 128 * 512;
  const unsigned short* Bb = Bm + (size_t)cb * 128 * 512;

  const f32x4 zero4 = {0.f, 0.f, 0.f, 0.f};
  f32x4 acc[4][4];
  #pragma unroll
  for (int i = 0; i < 4; ++i)
    #pragma unroll
    for (int j = 0; j < 4; ++j) acc[i][j] = zero4;

  stage_tile(Ab, 512, A0, tid);
  stage_tile(Bb, 512, B0, tid);
  __syncthreads();

  const int wr = wid >> 1, wc = wid & 1;

  for (int kb = 0; kb < 8; ++kb){
    unsigned short* Acur = (kb & 1) ? A1 : A0;
    unsigned short* Bcur = (kb & 1) ? B1 : B0;
    if (kb < 7){
      stage_tile(Ab + (kb + 1) * 64, 512, (kb & 1) ? A0 : A1, tid);
      stage_tile(Bb + (kb + 1) * 64, 512, (kb & 1) ? B0 : B1, tid);
    }
    #pragma unroll
    for (int ks = 0; ks < 2; ++ks){
      bf16x8 af[4], bf[4];
      #pragma unroll
      for (int i = 0; i < 4; ++i) af[i] = frag_at(Acur, wr * 64 + i * 16 + lr, ks * 4 + lg);
      #pragma unroll
      for (int j = 0; j < 4; ++j) bf[j] = frag_at(Bcur, wc * 64 + j * 16 + lr, ks * 4 + lg);
      #pragma unroll
      for (int i = 0; i < 4; ++i)
        #pragma unroll
        for (int j = 0; j < 4; ++j)
          acc[i][j] = __builtin_amdgcn_mfma_f32_16x16x32_bf16(af[i], bf[j], acc[i][j], 0, 0, 0);
    }
    __syncthreads();
  }

  // epilogue: LDS tile stride 136 (16B-aligned rows, lg-groups 16 banks apart)
  unsigned short* eL = SH;
  #pragma unroll
  for (int j = 0; j < 4; ++j){
    int lcol = wc * 64 + j * 16 + lr;
    #pragma unroll
    for (int i = 0; i < 4; ++i){
      int lrow0 = wr * 64 + i * 16 + lg * 4;
      #pragma unroll
      for (int r = 0; r < 4; ++r)
        eL[(lrow0 + r) * 136 + lcol] = f2bf(acc[i][j][r] * scale);
    }
  }
  __syncthreads();
  #pragma unroll
  for (int q = 0; q < 8; ++q){
    int idx = q * 256 + tid;
    int row = idx >> 4, col = (idx & 15) * 8;
    *(u16x8*)(&C[(size_t)(rb * 128 + row) * N + cb * 128 + col]) =
        *(const u16x8*)(&eL[row * 136 + col]);
  }
}

// ---------- S = G * X^T, fp16 out. grid = nbt*64, XCD-chunked. ----------
__global__ __launch_bounds__(256, 2)
void k_gemm_qk(const unsigned short* __restrict__ Gb, const unsigned short* __restrict__ Xb,
               unsigned short* __restrict__ S, int bt0){
  __shared__ __align__(16) unsigned short SH[32768];
  unsigned short* A0 = SH;
  unsigned short* A1 = SH + 8192;
  unsigned short* B0 = SH + 16384;
  unsigned short* B1 = SH + 24576;
  const int tid = threadIdx.x;
  const int l  = tid & 63;
  const int wid = tid >> 6;
  const int lr = l & 15;
  const int lg = l >> 4;
  const int cpx = gridDim.x >> 3;
  const int wg = (blockIdx.x & 7) * cpx + (blockIdx.x >> 3);
  const int btl = wg >> 6;
  const int bt = bt0 + btl;
  const int tile = wg & 63;
  const int rb = tile >> 3, cb = tile & 7;
  const unsigned short* Ab = Gb + ((size_t)bt << 19) + (size_t)rb * 128 * 512;
  const unsigned short* Bb = Xb + ((size_t)bt << 19) + (size_t)cb * 128 * 512;
  unsigned short* Cb = S + ((size_t)btl << 20);

  const f32x4 zero4 = {0.f, 0.f, 0.f, 0.f};
  f32x4 acc[4][4];
  #pragma unroll
  for (int i = 0; i < 4; ++i)
    #pragma unroll
    for (int j = 0; j < 4; ++j) acc[i][j] = zero4;

  stage_tile(Ab, 512, A0, tid);
  stage_tile(Bb, 512, B0, tid);
  __syncthreads();

  const int wr = wid >> 1, wc = wid & 1;

  for (int kb = 0; kb < 8; ++kb){
    unsigned short* Acur = (kb & 1) ? A1 : A0;
    unsigned short* Bcur = (kb & 1) ? B1 : B0;
    if (kb < 7){
      stage_tile(Ab + (kb + 1) * 64, 512, (kb & 1) ? A0 : A1, tid);
      stage_tile(Bb + (kb + 1) * 64, 512, (kb & 1) ? B0 : B1, tid);
    }
    #pragma unroll
    for (int ks = 0; ks < 2; ++ks){
      bf16x8 af[4], bf[4];
      #pragma unroll
      for (int i = 0; i < 4; ++i) af[i] = frag_at(Acur, wr * 64 + i * 16 + lr, ks * 4 + lg);
      #pragma unroll
      for (int j = 0; j < 4; ++j) bf[j] = frag_at(Bcur, wc * 64 + j * 16 + lr, ks * 4 + lg);
      #pragma unroll
      for (int i = 0; i < 4; ++i)
        #pragma unroll
        for (int j = 0; j < 4; ++j)
          acc[i][j] = __builtin_amdgcn_mfma_f32_16x16x32_bf16(af[i], bf[j], acc[i][j], 0, 0, 0);
    }
    __syncthreads();
  }

  unsigned short* eL = SH;
  #pragma unroll
  for (int j = 0; j < 4; ++j){
    int lcol = wc * 64 + j * 16 + lr;
    #pragma unroll
    for (int i = 0; i < 4; ++i){
      int lrow0 = wr * 64 + i * 16 + lg * 4;
      #pragma unroll
      for (int r = 0; r < 4; ++r){
        _Float16 h = (_Float16)acc[i][j][r];
        eL[(lrow0 + r) * 136 + lcol] = __builtin_bit_cast(unsigned short, h);
      }
    }
  }
  __syncthreads();
  #pragma unroll
  for (int q = 0; q < 8; ++q){
    int idx = q * 256 + tid;
    int row = idx >> 4, col = (idx & 15) * 8;
    *(u16x8*)(&Cb[((size_t)(rb * 128 + row) << 10) + cb * 128 + col]) =
        *(const u16x8*)(&eL[row * 136 + col]);
  }
}

// ---------- softmax rows in place: fp16 S (+vcol bias) -> bf16 P = w[t]*exp/l ----------
__global__ __launch_bounds__(256)
void k_softmax(unsigned short* __restrict__ S, const float* __restrict__ vcol,
               const float* __restrict__ tfw, int bt0){
  const int wid = threadIdx.x >> 6, l = threadIdx.x & 63;
  const size_t row = (size_t)blockIdx.x * 4 + wid;
  const int bt = bt0 + (int)(row >> 10);
  const int t = bt % 3;
  float t0 = tfw[0], t1 = tfw[1], t2 = tfw[2];
  float tm = fmaxf(t0, fmaxf(t1, t2));
  float e0 = __expf(t0 - tm), e1 = __expf(t1 - tm), e2 = __expf(t2 - tm);
  float w = (t == 0 ? e0 : (t == 1 ? e1 : e2)) / (e0 + e1 + e2);

  const float* vr = vcol + ((size_t)bt << 10) + l * 16;
  unsigned short* rp = S + (row << 10) + l * 16;
  u16x8 a = *(const u16x8*)rp;
  u16x8 b = *(const u16x8*)(rp + 8);
  f32x4 va0 = *(const f32x4*)(vr), va1 = *(const f32x4*)(vr + 4);
  f32x4 va2 = *(const f32x4*)(vr + 8), va3 = *(const f32x4*)(vr + 12);
  float x[16];
  #pragma unroll
  for (int j = 0; j < 8; ++j){
    x[j]     = (float)__builtin_bit_cast(_Float16, (unsigned short)a[j]);
    x[8 + j] = (float)__builtin_bit_cast(_Float16, (unsigned short)b[j]);
  }
  x[0] += va0[0]; x[1] += va0[1]; x[2]  += va0[2]; x[3]  += va0[3];
  x[4] += va1[0]; x[5] += va1[1]; x[6]  += va1[2]; x[7]  += va1[3];
  x[8] += va2[0]; x[9] += va2[1]; x[10] += va2[2]; x[11] += va2[3];
  x[12]+= va3[0]; x[13]+= va3[1]; x[14] += va3[2]; x[15] += va3[3];
  float m = x[0];
  #pragma unroll
  for (int j = 1; j < 16; ++j) m = fmaxf(m, x[j]);
  m = fmaxf(m, __shfl_xor(m, 1));
  m = fmaxf(m, __shfl_xor(m, 2));
  m = fmaxf(m, __shfl_xor(m, 4));
  m = fmaxf(m, __shfl_xor(m, 8));
  m = fmaxf(m, __shfl_xor(m, 16));
  m = fmaxf(m, __shfl_xor(m, 32));
  float s = 0.f;
  #pragma unroll
  for (int j = 0; j < 16; ++j){ x[j] = __expf(x[j] - m); s += x[j]; }
  s += __shfl_xor(s, 1);
  s += __shfl_xor(s, 2);
  s += __shfl_xor(s, 4);
  s += __shfl_xor(s, 8);
  s += __shfl_xor(s, 16);
  s += __shfl_xor(s, 32);
  float sc = w / s;
  u16x8 oa, ob;
  #pragma unroll
  for (int j = 0; j < 8; ++j){
    oa[j] = f2bf(x[j] * sc);
    ob[j] = f2bf(x[8 + j] * sc);
  }
  *(u16x8*)rp = oa;
  *(u16x8*)(rp + 8) = ob;
}

// ---------- Z[b] = sum_t P[b,t] * X[b,t]  (bf16 out, K=3072). grid = nb*32 ----------
__global__ __launch_bounds__(256, 2)
void k_gemm_px(const unsigned short* __restrict__ P, const unsigned short* __restrict__ Xt,
               unsigned short* __restrict__ Z, int b0){
  __shared__ __align__(16) unsigned short SH[32768];
  unsigned short* A0 = SH;
  unsigned short* A1 = SH + 8192;
  unsigned short* B0 = SH + 16384;
  unsigned short* B1 = SH + 24576;
  const int tid = threadIdx.x;
  const int l  = tid & 63;
  const int wid = tid >> 6;
  const int lr = l & 15;
  const int lg = l >> 4;
  const int cpx = gridDim.x >> 3;
  const int wg = (blockIdx.x & 7) * cpx + (blockIdx.x >> 3);
  const int bl = wg >> 5;
  const int b = b0 + bl;
  const int tile = wg & 31;
  const int rb = tile >> 2, cb = tile & 3;

  const f32x4 zero4 = {0.f, 0.f, 0.f, 0.f};
  f32x4 acc[4][4];
  #pragma unroll
  for (int i = 0; i < 4; ++i)
    #pragma unroll
    for (int j = 0; j < 4; ++j) acc[i][j] = zero4;

  {
    const unsigned short* Ab = P  + ((size_t)(bl * 3) << 20) + (size_t)rb * 128 * 1024;
    const unsigned short* Bb = Xt + ((size_t)(b * 3) << 19) + (size_t)cb * 128 * 1024;
    stage_tile(Ab, 1024, A0, tid);
    stage_tile(Bb, 1024, B0, tid);
  }
  __syncthreads();

  const int wr = wid >> 1, wc = wid & 1;

  #pragma unroll 2
  for (int kb = 0; kb < 48; ++kb){
    unsigned short* Acur = (kb & 1) ? A1 : A0;
    unsigned short* Bcur = (kb & 1) ? B1 : B0;
    if (kb < 47){
      int kn = kb + 1;
      int t = kn >> 4, kk = kn & 15;
      const unsigned short* Ab = P  + ((size_t)(bl * 3 + t) << 20) + (size_t)rb * 128 * 1024 + kk * 64;
      const unsigned short* Bb = Xt + ((size_t)(b * 3 + t) << 19) + (size_t)cb * 128 * 1024 + kk * 64;
      stage_tile(Ab, 1024, (kb & 1) ? A0 : A1, tid);
      stage_tile(Bb, 1024, (kb & 1) ? B0 : B1, tid);
    }
    #pragma unroll
    for (int ks = 0; ks < 2; ++ks){
      bf16x8 af[4], bf[4];
      #pragma unroll
      for (int i = 0; i < 4; ++i) af[i] = frag_at(Acur, wr * 64 + i * 16 + lr, ks * 4 + lg);
      #pragma unroll
      for (int j = 0; j < 4; ++j) bf[j] = frag_at(Bcur, wc * 64 + j * 16 + lr, ks * 4 + lg);
      #pragma unroll
      for (int i = 0; i < 4; ++i)
        #pragma unroll
        for (int j = 0; j < 4; ++j)
          acc[i][j] = __builtin_amdgcn_mfma_f32_16x16x32_bf16(af[i], bf[j], acc[i][j], 0, 0, 0);
    }
    __syncthreads();
  }

  unsigned short* eL = SH;
  #pragma unroll
  for (int j = 0; j < 4; ++j){
    int lcol = wc * 64 + j * 16 + lr;
    #pragma unroll
    for (int i = 0; i < 4; ++i){
      int lrow0 = wr * 64 + i * 16 + lg * 4;
      #pragma unroll
      for (int r = 0; r < 4; ++r)
        eL[(lrow0 + r) * 136 + lcol] = f2bf(acc[i][j][r]);
    }
  }
  __syncthreads();
  unsigned short* Cb = Z + ((size_t)b << 19);
  #pragma unroll
  for (int q = 0; q < 8; ++q){
    int idx = q * 256 + tid;
    int row = idx >> 4, col = (idx & 15) * 8;
    *(u16x8*)(&Cb[(size_t)(rb * 128 + row) * 512 + cb * 128 + col]) =
        *(const u16x8*)(&eL[row * 136 + col]);
  }
}

// ---------- out(f32) = Z * Wv^T + bv. M=16384, N=512, K=512. grid 512 ----------
__global__ __launch_bounds__(256, 2)
void k_gemm_zo(const unsigned short* __restrict__ Z, const unsigned short* __restrict__ Wv16,
               const float* __restrict__ bv, float* __restrict__ out){
  __shared__ __align__(16) unsigned short SH[32768];
  unsigned short* A0 = SH;
  unsigned short* A1 = SH + 8192;
  unsigned short* B0 = SH + 16384;
  unsigned short* B1 = SH + 24576;
  const int tid = threadIdx.x;
  const int l  = tid & 63;
  const int wid = tid >> 6;
  const int lr = l & 15;
  const int lg = l >> 4;
  const int cpx = gridDim.x >> 3;
  const int wg = (blockIdx.x & 7) * cpx + (blockIdx.x >> 3);
  const int rb = wg >> 2, cb = wg & 3;
  const unsigned short* Ab = Z + (size_t)rb * 128 * 512;
  const unsigned short* Bb = Wv16 + (size_t)cb * 128 * 512;

  const f32x4 zero4 = {0.f, 0.f, 0.f, 0.f};
  f32x4 acc[4][4];
  #pragma unroll
  for (int i = 0; i < 4; ++i)
    #pragma unroll
    for (int j = 0; j < 4; ++j) acc[i][j] = zero4;

  stage_tile(Ab, 512, A0, tid);
  stage_tile(Bb, 512, B0, tid);
  __syncthreads();

  const int wr = wid >> 1, wc = wid & 1;

  for (int kb = 0; kb < 8; ++kb){
    unsigned short* Acur = (kb & 1) ? A1 : A0;
    unsigned short* Bcur = (kb & 1) ? B1 : B0;
    if (kb < 7){
      stage_tile(Ab + (kb + 1) * 64, 512, (kb & 1) ? A0 : A1, tid);
      stage_tile(Bb + (kb + 1) * 64, 512, (kb & 1) ? B0 : B1, tid);
    }
    #pragma unroll
    for (int ks = 0; ks < 2; ++ks){
      bf16x8 af[4], bf[4];
      #pragma unroll
      for (int i = 0; i < 4; ++i) af[i] = frag_at(Acur, wr * 64 + i * 16 + lr, ks * 4 + lg);
      #pragma unroll
      for (int j = 0; j < 4; ++j) bf[j] = frag_at(Bcur, wc * 64 + j * 16 + lr, ks * 4 + lg);
      #pragma unroll
      for (int i = 0; i < 4; ++i)
        #pragma unroll
        for (int j = 0; j < 4; ++j)
          acc[i][j] = __builtin_amdgcn_mfma_f32_16x16x32_bf16(af[i], bf[j], acc[i][j], 0, 0, 0);
    }
    __syncthreads();
  }

  // direct f32 stores (pv-proven pattern)
  #pragma unroll
  for (int j = 0; j < 4; ++j){
    int col = cb * 128 + wc * 64 + j * 16 + lr;
    float bc = bv[col];
    #pragma unroll
    for (int i = 0; i < 4; ++i){
      int row0 = rb * 128 + wr * 64 + i * 16 + lg * 4;
      #pragma unroll
      for (int r = 0; r < 4; ++r)
        out[(size_t)(row0 + r) * 512 + col] = acc[i][j][r] + bc;
    }
  }
}

extern "C" void kernel_launch(void* const* d_in, const int* in_sizes, int n_in,
                              void* d_out, int out_size, void* d_ws, size_t ws_size,
                              hipStream_t stream){
  (void)in_sizes; (void)n_in; (void)out_size;
  const float* f4h = (const float*)d_in[0];
  const float* f1d = (const float*)d_in[1];
  const float* f1w = (const float*)d_in[2];
  const float* Wq  = (const float*)d_in[3];
  const float* bq  = (const float*)d_in[4];
  const float* Wk  = (const float*)d_in[5];
  const float* bk  = (const float*)d_in[6];
  const float* Wv  = (const float*)d_in[7];
  const float* bv  = (const float*)d_in[8];
  const float* tfw = (const float*)d_in[9];
  (void)bk;  // row-constant in scores: cancels in softmax
  float* out = (float*)d_out;

  const size_t N48 = (size_t)48 * 1024 * 512;
  unsigned short* Gb   = (unsigned short*)d_ws;    // Z overlays Gb after qk
  unsigned short* Xb   = Gb + N48;
  unsigned short* Xt   = Xb + N48;
  float*          vcol = (float*)(Xt + N48);       // 49152 f32
  unsigned short* Wv16 = (unsigned short*)(vcol + 49152);
  unsigned short* WqT  = Wv16 + 262144;            // Sb overlay starts here
  unsigned short* WkT  = WqT + 262144;
  unsigned short* Mt   = WkT + 262144;
  float*          w1   = (float*)(Mt + 262144);    // dead before Sb written
  unsigned short* Sb   = WqT;
  unsigned short* Zb   = Gb;

  const float SC = 0.04419417382415922f;           // 1/sqrt(512)
  const size_t base = 3 * N48 * 2 + 49152 * 4 + 262144 * 2;
  const size_t s_full = (size_t)48 * 1024 * 1024 * 2;

  k_prep<<<312, 256, 0, stream>>>(Wq, Wk, Wv, bq, WqT, WkT, Wv16, w1, vcol);
  k_conv<<<6144, 256, 0, stream>>>(f4h, f1d, f1w, w1, Xb, Xt, vcol);
  k_gemm_nt<<<16, 256, 0, stream>>>(WkT, WqT, Mt, 512, SC);     // Mt = SC*WkT*WqT^T
  k_gemm_nt<<<1536, 256, 0, stream>>>(Xb, Mt, Gb, 512, 1.0f);   // Gb = Xb * Mt^T

  if (ws_size >= base + s_full){
    k_gemm_qk<<<3072, 256, 0, stream>>>(Gb, Xb, Sb, 0);
    k_softmax<<<12288, 256, 0, stream>>>(Sb, vcol, tfw, 0);
    k_gemm_px<<<512, 256, 0, stream>>>(Sb, Xt, Zb, 0);
  } else {
    for (int h = 0; h < 2; ++h){
      int bt0 = h * 24;
      k_gemm_qk<<<1536, 256, 0, stream>>>(Gb, Xb, Sb, bt0);
      k_softmax<<<6144, 256, 0, stream>>>(Sb, vcol, tfw, bt0);
      k_gemm_px<<<256, 256, 0, stream>>>(Sb, Xt, Zb, h * 8);
    }
  }
  k_gemm_zo<<<512, 256, 0, stream>>>(Zb, Wv16, bv, out);
}

// Round 8
// 265.706 us; speedup vs baseline: 1.0162x; 1.0081x over previous
//
#include <hip/hip_runtime.h>
#include <cstdint>

typedef __bf16 bf16x8 __attribute__((ext_vector_type(8)));
typedef unsigned short u16x8 __attribute__((ext_vector_type(8)));
typedef unsigned short u16x4 __attribute__((ext_vector_type(4)));
typedef float f32x4 __attribute__((ext_vector_type(4)));

// B=16, S=1024, D=512, T=3, BT=48
// Xb [bt][s][d] bf16 ; Xt [bt][d][s] bf16 ; Gb [bt][s][d'] bf16 (= X * (SC*Wq^T*Wk))
// Sb: [bt][q][k] fp16 scores -> bf16 P=w_t*exp/l in place
// Z  [b][s][d] bf16 (= sum_t P_t X_t), overlays Gb ; out = Z*Wv^T + bv

__device__ __forceinline__ unsigned short f2bf(float x){
  unsigned u = __float_as_uint(x);
  u += 0x7fffu + ((u >> 16) & 1u);
  return (unsigned short)(u >> 16);
}

__device__ __forceinline__ void gload16(const void* src, void* dst){
  auto g = reinterpret_cast<const uint32_t __attribute__((address_space(1)))*>(
             reinterpret_cast<uintptr_t>(src));
  auto l = reinterpret_cast<uint32_t __attribute__((address_space(3)))*>(
             reinterpret_cast<uintptr_t>(dst));
  __builtin_amdgcn_global_load_lds(g, l, 16, 0, 0);
}

// 512-thread stager: one 128x64 bf16 tile, linear LDS, inverse-swizzled global source.
__device__ __forceinline__ void stage512(const unsigned short* __restrict__ g, size_t ld,
                                         unsigned short* l, int tid){
  #pragma unroll
  for (int i = 0; i < 2; ++i){
    int j = i * 512 + tid;
    int r = j >> 3, cc = j & 7;
    int c = cc ^ (r & 7);
    gload16(g + (size_t)r * ld + c * 8, l + (size_t)(i * 512 + (tid & 448)) * 8);
  }
}

__device__ __forceinline__ bf16x8 frag_at(const unsigned short* l, int row, int kch){
  int ch = kch ^ (row & 7);
  return *(const bf16x8*)(l + (row << 6) + (ch << 3));
}

// ---------- merged prologue: conv_wt (0-127), conv_wv (128-255), w1 (256-263), vcol zero (264-311) ----------
__global__ void k_prep(const float* __restrict__ Wq, const float* __restrict__ Wk,
                       const float* __restrict__ Wv, const float* __restrict__ bq,
                       unsigned short* __restrict__ WqT, unsigned short* __restrict__ WkT,
                       unsigned short* __restrict__ Wv16, float* __restrict__ w1,
                       float* __restrict__ vcol){
  __shared__ float sh[64 * 65];
  const int bi = blockIdx.x;
  const int tid = threadIdx.x;
  if (bi < 128){
    const float* src = (bi & 64) ? Wk : Wq;
    unsigned short* dst = (bi & 64) ? WkT : WqT;
    int te = (bi >> 3) & 7, td = bi & 7;
    #pragma unroll
    for (int i = 0; i < 4; ++i){
      int q = i * 256 + tid;
      int r = q >> 4, c4 = q & 15;
      f32x4 v = *(const f32x4*)(src + (size_t)(te * 64 + r) * 512 + td * 64 + c4 * 4);
      sh[r * 65 + c4 * 4 + 0] = v[0]; sh[r * 65 + c4 * 4 + 1] = v[1];
      sh[r * 65 + c4 * 4 + 2] = v[2]; sh[r * 65 + c4 * 4 + 3] = v[3];
    }
    __syncthreads();
    #pragma unroll
    for (int i = 0; i < 2; ++i){
      int q = i * 256 + tid;
      int r = q >> 3, c8 = q & 7;
      u16x8 o;
      #pragma unroll
      for (int j = 0; j < 8; ++j) o[j] = f2bf(sh[(c8 * 8 + j) * 65 + r]);
      *(u16x8*)(dst + (size_t)(td * 64 + r) * 512 + te * 64 + c8 * 8) = o;
    }
  } else if (bi < 256){
    size_t e = ((size_t)(bi - 128) * 256 + tid) * 8;
    f32x4 v0 = *(const f32x4*)(Wv + e), v1 = *(const f32x4*)(Wv + e + 4);
    u16x8 o;
    o[0] = f2bf(v0[0]); o[1] = f2bf(v0[1]); o[2] = f2bf(v0[2]); o[3] = f2bf(v0[3]);
    o[4] = f2bf(v1[0]); o[5] = f2bf(v1[1]); o[6] = f2bf(v1[2]); o[7] = f2bf(v1[3]);
    *(u16x8*)(Wv16 + e) = o;
  } else if (bi < 264){
    int d = (bi - 256) * 64 + (tid & 63);
    int eq = tid >> 6;
    float s = 0.f;
    #pragma unroll 8
    for (int e = eq * 128; e < eq * 128 + 128; ++e) s += Wk[(size_t)e * 512 + d] * bq[e];
    sh[eq * 64 + (tid & 63)] = s;
    __syncthreads();
    if (eq == 0)
      w1[d] = (sh[tid] + sh[64 + tid] + sh[128 + tid] + sh[192 + tid]) * 0.04419417382415922f;
  } else {
    f32x4 z = {0.f, 0.f, 0.f, 0.f};
    *(f32x4*)(vcol + ((size_t)(bi - 264) * 256 + tid) * 4) = z;
  }
}

// ---------- features fp32 -> bf16 Xb + Xt (transposed) + vcol = X*w1 ----------
__global__ void k_conv(const float* __restrict__ f0, const float* __restrict__ f1,
                       const float* __restrict__ f2, const float* __restrict__ w1,
                       unsigned short* __restrict__ Xb, unsigned short* __restrict__ Xt,
                       float* __restrict__ vcol){
  __shared__ float tl[64 * 65];
  const int bi = blockIdx.x;
  const int tid = threadIdx.x;
  const int bt = bi >> 7;
  const int st = (bi >> 3) & 15, dt = bi & 7;
  const int b = bt / 3, t = bt % 3;
  const int s0 = st * 64, d0 = dt * 64;
  const float* src = (t == 0 ? f0 : (t == 1 ? f1 : f2)) + ((size_t)b << 19)
                   + (size_t)s0 * 512 + d0;
  #pragma unroll
  for (int q = 0; q < 4; ++q){
    int j = q * 256 + tid;
    int r = j >> 4, c4 = (j & 15) * 4;
    f32x4 v = *(const f32x4*)(src + (size_t)r * 512 + c4);
    u16x4 o;
    o[0] = f2bf(v[0]); o[1] = f2bf(v[1]); o[2] = f2bf(v[2]); o[3] = f2bf(v[3]);
    *(u16x4*)(Xb + ((size_t)bt << 19) + (size_t)(s0 + r) * 512 + d0 + c4) = o;
    tl[r * 65 + c4 + 0] = v[0]; tl[r * 65 + c4 + 1] = v[1];
    tl[r * 65 + c4 + 2] = v[2]; tl[r * 65 + c4 + 3] = v[3];
    f32x4 wv = *(const f32x4*)(w1 + d0 + c4);
    float p = v[0]*wv[0] + v[1]*wv[1] + v[2]*wv[2] + v[3]*wv[3];
    p += __shfl_xor(p, 1); p += __shfl_xor(p, 2);
    p += __shfl_xor(p, 4); p += __shfl_xor(p, 8);
    if ((tid & 15) == 0) atomicAdd(vcol + ((size_t)bt << 10) + s0 + r, p);
  }
  __syncthreads();
  #pragma unroll
  for (int q = 0; q < 2; ++q){
    int j = q * 256 + tid;
    int d = j >> 3, sc = (j & 7) * 8;
    u16x8 o;
    #pragma unroll
    for (int k = 0; k < 8; ++k) o[k] = f2bf(tl[(sc + k) * 65 + d]);
    *(u16x8*)(Xt + ((size_t)bt << 19) + (size_t)(d0 + d) * 1024 + s0 + sc) = o;
  }
}

// ---------- C(bf16) = A * B^T * scale. K=512. 512 threads, 8 waves. ----------
__global__ __launch_bounds__(512, 4)
void k_gemm_nt(const unsigned short* __restrict__ A, const unsigned short* __restrict__ Bm,
               unsigned short* __restrict__ C, int N, float scale){
  __shared__ __align__(16) unsigned short SH[32768];
  unsigned short* A0 = SH;
  unsigned short* A1 = SH + 8192;
  unsigned short* B0 = SH + 16384;
  unsigned short* B1 = SH + 24576;
  const int tid = threadIdx.x;
  const int l  = tid & 63;
  const int wid = tid >> 6;
  const int lr = l & 15;
  const int lg = l >> 4;
  const int wr = wid >> 1, wc = wid & 1;   // 4 x 2 wave grid: 32 rows x 64 cols each
  const int cpx = gridDim.x >> 3;
  const int wg = (blockIdx.x & 7) * cpx + (blockIdx.x >> 3);
  const int nbc = N >> 7;
  const int rb = wg / nbc, cb = wg % nbc;
  const unsigned short* Ab = A + (size_t)rb * 128 * 512;
  const unsigned short* Bb = Bm + (size_t)cb * 128 * 512;

  const f32x4 zero4 = {0.f, 0.f, 0.f, 0.f};
  f32x4 acc[2][4];
  #pragma unroll
  for (int i = 0; i < 2; ++i)
    #pragma unroll
    for (int j = 0; j < 4; ++j) acc[i][j] = zero4;

  stage512(Ab, 512, A0, tid);
  stage512(Bb, 512, B0, tid);
  __syncthreads();

  for (int kb = 0; kb < 8; ++kb){
    unsigned short* Acur = (kb & 1) ? A1 : A0;
    unsigned short* Bcur = (kb & 1) ? B1 : B0;
    if (kb < 7){
      stage512(Ab + (kb + 1) * 64, 512, (kb & 1) ? A0 : A1, tid);
      stage512(Bb + (kb + 1) * 64, 512, (kb & 1) ? B0 : B1, tid);
    }
    #pragma unroll
    for (int ks = 0; ks < 2; ++ks){
      bf16x8 af[2], bf[4];
      #pragma unroll
      for (int i = 0; i < 2; ++i) af[i] = frag_at(Acur, wr * 32 + i * 16 + lr, ks * 4 + lg);
      #pragma unroll
      for (int j = 0; j < 4; ++j) bf[j] = frag_at(Bcur, wc * 64 + j * 16 + lr, ks * 4 + lg);
      #pragma unroll
      for (int i = 0; i < 2; ++i)
        #pragma unroll
        for (int j = 0; j < 4; ++j)
          acc[i][j] = __builtin_amdgcn_mfma_f32_16x16x32_bf16(af[i], bf[j], acc[i][j], 0, 0, 0);
    }
    __syncthreads();
  }

  unsigned short* eL = SH;
  #pragma unroll
  for (int j = 0; j < 4; ++j){
    int lcol = wc * 64 + j * 16 + lr;
    #pragma unroll
    for (int i = 0; i < 2; ++i){
      int lrow0 = wr * 32 + i * 16 + lg * 4;
      #pragma unroll
      for (int r = 0; r < 4; ++r)
        eL[(lrow0 + r) * 136 + lcol] = f2bf(acc[i][j][r] * scale);
    }
  }
  __syncthreads();
  #pragma unroll
  for (int q = 0; q < 4; ++q){
    int idx = q * 512 + tid;
    int row = idx >> 4, col = (idx & 15) * 8;
    *(u16x8*)(&C[(size_t)(rb * 128 + row) * N + cb * 128 + col]) =
        *(const u16x8*)(&eL[row * 136 + col]);
  }
}

// ---------- S = G * X^T, fp16 out. 512 threads. grid = nbt*64, XCD-chunked. ----------
__global__ __launch_bounds__(512, 4)
void k_gemm_qk(const unsigned short* __restrict__ Gb, const unsigned short* __restrict__ Xb,
               unsigned short* __restrict__ S, int bt0){
  __shared__ __align__(16) unsigned short SH[32768];
  unsigned short* A0 = SH;
  unsigned short* A1 = SH + 8192;
  unsigned short* B0 = SH + 16384;
  unsigned short* B1 = SH + 24576;
  const int tid = threadIdx.x;
  const int l  = tid & 63;
  const int wid = tid >> 6;
  const int lr = l & 15;
  const int lg = l >> 4;
  const int wr = wid >> 1, wc = wid & 1;
  const int cpx = gridDim.x >> 3;
  const int wg = (blockIdx.x & 7) * cpx + (blockIdx.x >> 3);
  const int btl = wg >> 6;
  const int bt = bt0 + btl;
  const int tile = wg & 63;
  const int rb = tile >> 3, cb = tile & 7;
  const unsigned short* Ab = Gb + ((size_t)bt << 19) + (size_t)rb * 128 * 512;
  const unsigned short* Bb = Xb + ((size_t)bt << 19) + (size_t)cb * 128 * 512;
  unsigned short* Cb = S + ((size_t)btl << 20);

  const f32x4 zero4 = {0.f, 0.f, 0.f, 0.f};
  f32x4 acc[2][4];
  #pragma unroll
  for (int i = 0; i < 2; ++i)
    #pragma unroll
    for (int j = 0; j < 4; ++j) acc[i][j] = zero4;

  stage512(Ab, 512, A0, tid);
  stage512(Bb, 512, B0, tid);
  __syncthreads();

  for (int kb = 0; kb < 8; ++kb){
    unsigned short* Acur = (kb & 1) ? A1 : A0;
    unsigned short* Bcur = (kb & 1) ? B1 : B0;
    if (kb < 7){
      stage512(Ab + (kb + 1) * 64, 512, (kb & 1) ? A0 : A1, tid);
      stage512(Bb + (kb + 1) * 64, 512, (kb & 1) ? B0 : B1, tid);
    }
    #pragma unroll
    for (int ks = 0; ks < 2; ++ks){
      bf16x8 af[2], bf[4];
      #pragma unroll
      for (int i = 0; i < 2; ++i) af[i] = frag_at(Acur, wr * 32 + i * 16 + lr, ks * 4 + lg);
      #pragma unroll
      for (int j = 0; j < 4; ++j) bf[j] = frag_at(Bcur, wc * 64 + j * 16 + lr, ks * 4 + lg);
      #pragma unroll
      for (int i = 0; i < 2; ++i)
        #pragma unroll
        for (int j = 0; j < 4; ++j)
          acc[i][j] = __builtin_amdgcn_mfma_f32_16x16x32_bf16(af[i], bf[j], acc[i][j], 0, 0, 0);
    }
    __syncthreads();
  }

  unsigned short* eL = SH;
  #pragma unroll
  for (int j = 0; j < 4; ++j){
    int lcol = wc * 64 + j * 16 + lr;
    #pragma unroll
    for (int i = 0; i < 2; ++i){
      int lrow0 = wr * 32 + i * 16 + lg * 4;
      #pragma unroll
      for (int r = 0; r < 4; ++r){
        _Float16 h = (_Float16)acc[i][j][r];
        eL[(lrow0 + r) * 136 + lcol] = __builtin_bit_cast(unsigned short, h);
      }
    }
  }
  __syncthreads();
  #pragma unroll
  for (int q = 0; q < 4; ++q){
    int idx = q * 512 + tid;
    int row = idx >> 4, col = (idx & 15) * 8;
    *(u16x8*)(&Cb[((size_t)(rb * 128 + row) << 10) + cb * 128 + col]) =
        *(const u16x8*)(&eL[row * 136 + col]);
  }
}

// ---------- softmax rows in place: fp16 S (+vcol bias) -> bf16 P = w[t]*exp/l ----------
__global__ __launch_bounds__(256)
void k_softmax(unsigned short* __restrict__ S, const float* __restrict__ vcol,
               const float* __restrict__ tfw, int bt0){
  const int wid = threadIdx.x >> 6, l = threadIdx.x & 63;
  const size_t row = (size_t)blockIdx.x * 4 + wid;
  const int bt = bt0 + (int)(row >> 10);
  const int t = bt % 3;
  float t0 = tfw[0], t1 = tfw[1], t2 = tfw[2];
  float tm = fmaxf(t0, fmaxf(t1, t2));
  float e0 = __expf(t0 - tm), e1 = __expf(t1 - tm), e2 = __expf(t2 - tm);
  float w = (t == 0 ? e0 : (t == 1 ? e1 : e2)) / (e0 + e1 + e2);

  const float* vr = vcol + ((size_t)bt << 10) + l * 16;
  unsigned short* rp = S + (row << 10) + l * 16;
  u16x8 a = *(const u16x8*)rp;
  u16x8 b = *(const u16x8*)(rp + 8);
  f32x4 va0 = *(const f32x4*)(vr), va1 = *(const f32x4*)(vr + 4);
  f32x4 va2 = *(const f32x4*)(vr + 8), va3 = *(const f32x4*)(vr + 12);
  float x[16];
  #pragma unroll
  for (int j = 0; j < 8; ++j){
    x[j]     = (float)__builtin_bit_cast(_Float16, (unsigned short)a[j]);
    x[8 + j] = (float)__builtin_bit_cast(_Float16, (unsigned short)b[j]);
  }
  x[0] += va0[0]; x[1] += va0[1]; x[2]  += va0[2]; x[3]  += va0[3];
  x[4] += va1[0]; x[5] += va1[1]; x[6]  += va1[2]; x[7]  += va1[3];
  x[8] += va2[0]; x[9] += va2[1]; x[10] += va2[2]; x[11] += va2[3];
  x[12]+= va3[0]; x[13]+= va3[1]; x[14] += va3[2]; x[15] += va3[3];
  float m = x[0];
  #pragma unroll
  for (int j = 1; j < 16; ++j) m = fmaxf(m, x[j]);
  m = fmaxf(m, __shfl_xor(m, 1));
  m = fmaxf(m, __shfl_xor(m, 2));
  m = fmaxf(m, __shfl_xor(m, 4));
  m = fmaxf(m, __shfl_xor(m, 8));
  m = fmaxf(m, __shfl_xor(m, 16));
  m = fmaxf(m, __shfl_xor(m, 32));
  float s = 0.f;
  #pragma unroll
  for (int j = 0; j < 16; ++j){ x[j] = __expf(x[j] - m); s += x[j]; }
  s += __shfl_xor(s, 1);
  s += __shfl_xor(s, 2);
  s += __shfl_xor(s, 4);
  s += __shfl_xor(s, 8);
  s += __shfl_xor(s, 16);
  s += __shfl_xor(s, 32);
  float sc = w / s;
  u16x8 oa, ob;
  #pragma unroll
  for (int j = 0; j < 8; ++j){
    oa[j] = f2bf(x[j] * sc);
    ob[j] = f2bf(x[8 + j] * sc);
  }
  *(u16x8*)rp = oa;
  *(u16x8*)(rp + 8) = ob;
}

// ---------- Z[b] = sum_t P[b,t] * X[b,t]  (bf16 out, K=3072). 512 threads. grid = nb*32 ----------
__global__ __launch_bounds__(512, 4)
void k_gemm_px(const unsigned short* __restrict__ P, const unsigned short* __restrict__ Xt,
               unsigned short* __restrict__ Z, int b0){
  __shared__ __align__(16) unsigned short SH[32768];
  unsigned short* A0 = SH;
  unsigned short* A1 = SH + 8192;
  unsigned short* B0 = SH + 16384;
  unsigned short* B1 = SH + 24576;
  const int tid = threadIdx.x;
  const int l  = tid & 63;
  const int wid = tid >> 6;
  const int lr = l & 15;
  const int lg = l >> 4;
  const int wr = wid >> 1, wc = wid & 1;
  const int cpx = gridDim.x >> 3;
  const int wg = (blockIdx.x & 7) * cpx + (blockIdx.x >> 3);
  const int bl = wg >> 5;
  const int b = b0 + bl;
  const int tile = wg & 31;
  const int rb = tile >> 2, cb = tile & 3;

  const f32x4 zero4 = {0.f, 0.f, 0.f, 0.f};
  f32x4 acc[2][4];
  #pragma unroll
  for (int i = 0; i < 2; ++i)
    #pragma unroll
    for (int j = 0; j < 4; ++j) acc[i][j] = zero4;

  {
    const unsigned short* Ab = P  + ((size_t)(bl * 3) << 20) + (size_t)rb * 128 * 1024;
    const unsigned short* Bb = Xt + ((size_t)(b * 3) << 19) + (size_t)cb * 128 * 1024;
    stage512(Ab, 1024, A0, tid);
    stage512(Bb, 1024, B0, tid);
  }
  __syncthreads();

  #pragma unroll 2
  for (int kb = 0; kb < 48; ++kb){
    unsigned short* Acur = (kb & 1) ? A1 : A0;
    unsigned short* Bcur = (kb & 1) ? B1 : B0;
    if (kb < 47){
      int kn = kb + 1;
      int t = kn >> 4, kk = kn & 15;
      const unsigned short* Ab = P  + ((size_t)(bl * 3 + t) << 20) + (size_t)rb * 128 * 1024 + kk * 64;
      const unsigned short* Bb = Xt + ((size_t)(b * 3 + t) << 19) + (size_t)cb * 128 * 1024 + kk * 64;
      stage512(Ab, 1024, (kb & 1) ? A0 : A1, tid);
      stage512(Bb, 1024, (kb & 1) ? B0 : B1, tid);
    }
    #pragma unroll
    for (int ks = 0; ks < 2; ++ks){
      bf16x8 af[2], bf[4];
      #pragma unroll
      for (int i = 0; i < 2; ++i) af[i] = frag_at(Acur, wr * 32 + i * 16 + lr, ks * 4 + lg);
      #pragma unroll
      for (int j = 0; j < 4; ++j) bf[j] = frag_at(Bcur, wc * 64 + j * 16 + lr, ks * 4 + lg);
      #pragma unroll
      for (int i = 0; i < 2; ++i)
        #pragma unroll
        for (int j = 0; j < 4; ++j)
          acc[i][j] = __builtin_amdgcn_mfma_f32_16x16x32_bf16(af[i], bf[j], acc[i][j], 0, 0, 0);
    }
    __syncthreads();
  }

  unsigned short* eL = SH;
  #pragma unroll
  for (int j = 0; j < 4; ++j){
    int lcol = wc * 64 + j * 16 + lr;
    #pragma unroll
    for (int i = 0; i < 2; ++i){
      int lrow0 = wr * 32 + i * 16 + lg * 4;
      #pragma unroll
      for (int r = 0; r < 4; ++r)
        eL[(lrow0 + r) * 136 + lcol] = f2bf(acc[i][j][r]);
    }
  }
  __syncthreads();
  unsigned short* Cb = Z + ((size_t)b << 19);
  #pragma unroll
  for (int q = 0; q < 4; ++q){
    int idx = q * 512 + tid;
    int row = idx >> 4, col = (idx & 15) * 8;
    *(u16x8*)(&Cb[(size_t)(rb * 128 + row) * 512 + cb * 128 + col]) =
        *(const u16x8*)(&eL[row * 136 + col]);
  }
}

// ---------- out(f32) = Z * Wv^T + bv. 512 threads. grid 512 ----------
__global__ __launch_bounds__(512, 4)
void k_gemm_zo(const unsigned short* __restrict__ Z, const unsigned short* __restrict__ Wv16,
               const float* __restrict__ bv, float* __restrict__ out){
  __shared__ __align__(16) unsigned short SH[32768];
  unsigned short* A0 = SH;
  unsigned short* A1 = SH + 8192;
  unsigned short* B0 = SH + 16384;
  unsigned short* B1 = SH + 24576;
  const int tid = threadIdx.x;
  const int l  = tid & 63;
  const int wid = tid >> 6;
  const int lr = l & 15;
  const int lg = l >> 4;
  const int wr = wid >> 1, wc = wid & 1;
  const int cpx = gridDim.x >> 3;
  const int wg = (blockIdx.x & 7) * cpx + (blockIdx.x >> 3);
  const int rb = wg >> 2, cb = wg & 3;
  const unsigned short* Ab = Z + (size_t)rb * 128 * 512;
  const unsigned short* Bb = Wv16 + (size_t)cb * 128 * 512;

  const f32x4 zero4 = {0.f, 0.f, 0.f, 0.f};
  f32x4 acc[2][4];
  #pragma unroll
  for (int i = 0; i < 2; ++i)
    #pragma unroll
    for (int j = 0; j < 4; ++j) acc[i][j] = zero4;

  stage512(Ab, 512, A0, tid);
  stage512(Bb, 512, B0, tid);
  __syncthreads();

  for (int kb = 0; kb < 8; ++kb){
    unsigned short* Acur = (kb & 1) ? A1 : A0;
    unsigned short* Bcur = (kb & 1) ? B1 : B0;
    if (kb < 7){
      stage512(Ab + (kb + 1) * 64, 512, (kb & 1) ? A0 : A1, tid);
      stage512(Bb + (kb + 1) * 64, 512, (kb & 1) ? B0 : B1, tid);
    }
    #pragma unroll
    for (int ks = 0; ks < 2; ++ks){
      bf16x8 af[2], bf[4];
      #pragma unroll
      for (int i = 0; i < 2; ++i) af[i] = frag_at(Acur, wr * 32 + i * 16 + lr, ks * 4 + lg);
      #pragma unroll
      for (int j = 0; j < 4; ++j) bf[j] = frag_at(Bcur, wc * 64 + j * 16 + lr, ks * 4 + lg);
      #pragma unroll
      for (int i = 0; i < 2; ++i)
        #pragma unroll
        for (int j = 0; j < 4; ++j)
          acc[i][j] = __builtin_amdgcn_mfma_f32_16x16x32_bf16(af[i], bf[j], acc[i][j], 0, 0, 0);
    }
    __syncthreads();
  }

  // direct f32 stores
  #pragma unroll
  for (int j = 0; j < 4; ++j){
    int col = cb * 128 + wc * 64 + j * 16 + lr;
    float bc = bv[col];
    #pragma unroll
    for (int i = 0; i < 2; ++i){
      int row0 = rb * 128 + wr * 32 + i * 16 + lg * 4;
      #pragma unroll
      for (int r = 0; r < 4; ++r)
        out[(size_t)(row0 + r) * 512 + col] = acc[i][j][r] + bc;
    }
  }
}

extern "C" void kernel_launch(void* const* d_in, const int* in_sizes, int n_in,
                              void* d_out, int out_size, void* d_ws, size_t ws_size,
                              hipStream_t stream){
  (void)in_sizes; (void)n_in; (void)out_size;
  const float* f4h = (const float*)d_in[0];
  const float* f1d = (const float*)d_in[1];
  const float* f1w = (const float*)d_in[2];
  const float* Wq  = (const float*)d_in[3];
  const float* bq  = (const float*)d_in[4];
  const float* Wk  = (const float*)d_in[5];
  const float* bk  = (const float*)d_in[6];
  const float* Wv  = (const float*)d_in[7];
  const float* bv  = (const float*)d_in[8];
  const float* tfw = (const float*)d_in[9];
  (void)bk;  // row-constant in scores: cancels in softmax
  float* out = (float*)d_out;

  const size_t N48 = (size_t)48 * 1024 * 512;
  unsigned short* Gb   = (unsigned short*)d_ws;    // Z overlays Gb after qk
  unsigned short* Xb   = Gb + N48;
  unsigned short* Xt   = Xb + N48;
  float*          vcol = (float*)(Xt + N48);       // 49152 f32
  unsigned short* Wv16 = (unsigned short*)(vcol + 49152);
  unsigned short* WqT  = Wv16 + 262144;            // Sb overlay starts here
  unsigned short* WkT  = WqT + 262144;
  unsigned short* Mt   = WkT + 262144;
  float*          w1   = (float*)(Mt + 262144);    // dead before Sb written
  unsigned short* Sb   = WqT;
  unsigned short* Zb   = Gb;

  const float SC = 0.04419417382415922f;           // 1/sqrt(512)
  const size_t base = 3 * N48 * 2 + 49152 * 4 + 262144 * 2;
  const size_t s_full = (size_t)48 * 1024 * 1024 * 2;

  k_prep<<<312, 256, 0, stream>>>(Wq, Wk, Wv, bq, WqT, WkT, Wv16, w1, vcol);
  k_conv<<<6144, 256, 0, stream>>>(f4h, f1d, f1w, w1, Xb, Xt, vcol);
  k_gemm_nt<<<16, 512, 0, stream>>>(WkT, WqT, Mt, 512, SC);     // Mt = SC*WkT*WqT^T
  k_gemm_nt<<<1536, 512, 0, stream>>>(Xb, Mt, Gb, 512, 1.0f);   // Gb = Xb * Mt^T

  if (ws_size >= base + s_full){
    k_gemm_qk<<<3072, 512, 0, stream>>>(Gb, Xb, Sb, 0);
    k_softmax<<<12288, 256, 0, stream>>>(Sb, vcol, tfw, 0);
    k_gemm_px<<<512, 512, 0, stream>>>(Sb, Xt, Zb, 0);
  } else {
    for (int h = 0; h < 2; ++h){
      int bt0 = h * 24;
      k_gemm_qk<<<1536, 512, 0, stream>>>(Gb, Xb, Sb, bt0);
      k_softmax<<<6144, 256, 0, stream>>>(Sb, vcol, tfw, bt0);
      k_gemm_px<<<256, 512, 0, stream>>>(Sb, Xt, Zb, h * 8);
    }
  }
  k_gemm_zo<<<512, 512, 0, stream>>>(Zb, Wv16, bv, out);
}